// Round 15
// baseline (704.769 us; speedup 1.0000x reference)
//
#include <hip/hip_runtime.h>
#include <hip/hip_bf16.h>

using bf16 = __hip_bfloat16;
typedef __bf16 bf16x8 __attribute__((ext_vector_type(8)));
typedef float f32x4 __attribute__((ext_vector_type(4)));
typedef int i32x4 __attribute__((ext_vector_type(4)));
typedef short short4v __attribute__((ext_vector_type(4)));
typedef short short8v __attribute__((ext_vector_type(8)));

#define DEV __device__ __forceinline__

// B=32, S=64, T=64 (dec 63), V=32000, E=256, H=512, 4H=2048

DEV unsigned short f2bf(float f) {  // RNE float->bf16
  unsigned u = __builtin_bit_cast(unsigned, f);
  u = (u + 0x7fffu + ((u >> 16) & 1u)) >> 16;
  return (unsigned short)u;
}

DEV f32x4 mfma16(bf16x8 a, bf16x8 b, f32x4 c) {
  return __builtin_amdgcn_mfma_f32_16x16x32_bf16(a, b, c, 0, 0, 0);
}

DEV bf16x8 cvt8(const float* p) {  // 8 fp32 -> bf16x8 (plain cached loads)
  f32x4 a = *(const f32x4*)p, b = *(const f32x4*)(p + 4);
  short8v o;
#pragma unroll
  for (int j = 0; j < 4; ++j) { o[j] = (short)f2bf(a[j]); o[j + 4] = (short)f2bf(b[j]); }
  return __builtin_bit_cast(bf16x8, o);
}

// ---- LLC-coherent (bypass L1+L2) access helpers ------------------------------
DEV void llc_load16(bf16x8* dst, const bf16* p) {  // issue only; caller waits vmcnt
  i32x4 r;
  asm volatile("global_load_dwordx4 %0, %1, off sc0 sc1" : "=v"(r) : "v"(p) : "memory");
  *dst = __builtin_bit_cast(bf16x8, r);
}
DEV void g_load16(bf16x8* dst, const bf16* p) {  // plain (L1/L2-cached), asm-ordered
  i32x4 r;
  asm volatile("global_load_dwordx4 %0, %1, off" : "=v"(r) : "v"(p) : "memory");
  *dst = __builtin_bit_cast(bf16x8, r);
}
DEV void llc_store16(void* p, short8v v) {
  asm volatile("global_store_dwordx4 %0, %1, off sc0 sc1"
               :: "v"(p), "v"(__builtin_bit_cast(i32x4, v)) : "memory");
}
DEV void llc_store_f32(float* p, float v) {
  asm volatile("global_store_dword %0, %1, off sc0 sc1" :: "v"(p), "v"(v) : "memory");
}
DEV bool valid16(bf16x8 v) {  // no dword still holds the 0xFFFFFFFF poison
  i32x4 u = __builtin_bit_cast(i32x4, v);
  return (u[0] != -1) && (u[1] != -1) && (u[2] != -1) && (u[3] != -1);
}

// Data-is-flag slab read with cheap wait loop (R12-verified ordering:
// issue AFTER the x phase — pre-issuing before it regressed 2x in R13).
DEV void poll_slab(const bf16* base, int fl, int koff, bf16x8 a0[4], bf16x8 a1[4]) {
  const bf16* r0 = base + (long)fl * 512 + koff;
  const bf16* r1 = base + (long)(fl + 16) * 512 + koff;
#pragma unroll
  for (int kt = 0; kt < 4; ++kt) {
    llc_load16(&a0[kt], r0 + kt * 32);
    llc_load16(&a1[kt], r1 + kt * 32);
  }
  asm volatile("s_waitcnt vmcnt(0)" ::: "memory");
  {
    bool ok = true;
#pragma unroll
    for (int kt = 0; kt < 4; ++kt) ok = ok && valid16(a0[kt]) && valid16(a1[kt]);
    if (__all(ok)) return;
  }
  // sentinel wait: 1 dword per producer chunk (8x less traffic than full slab)
  while (true) {
    unsigned s0, s1, s2, s3;
    asm volatile(
        "global_load_dword %0, %4, off sc0 sc1\n\t"
        "global_load_dword %1, %5, off sc0 sc1\n\t"
        "global_load_dword %2, %6, off sc0 sc1\n\t"
        "global_load_dword %3, %7, off sc0 sc1\n\t"
        "s_waitcnt vmcnt(0)"
        : "=v"(s0), "=v"(s1), "=v"(s2), "=v"(s3)
        : "v"(r0), "v"(r0 + 32), "v"(r0 + 64), "v"(r0 + 96)
        : "memory");
    bool ok = (s0 != 0xFFFFFFFFu) & (s1 != 0xFFFFFFFFu) & (s2 != 0xFFFFFFFFu) &
              (s3 != 0xFFFFFFFFu);
    if (__all(ok)) break;
    __builtin_amdgcn_s_sleep(1);
  }
  // full reload + validate (covers row fl+16 and every dword)
  while (true) {
#pragma unroll
    for (int kt = 0; kt < 4; ++kt) {
      llc_load16(&a0[kt], r0 + kt * 32);
      llc_load16(&a1[kt], r1 + kt * 32);
    }
    asm volatile("s_waitcnt vmcnt(0)" ::: "memory");
    bool ok = true;
#pragma unroll
    for (int kt = 0; kt < 4; ++kt) ok = ok && valid16(a0[kt]) && valid16(a1[kt]);
    if (__all(ok)) break;
    __builtin_amdgcn_s_sleep(1);
  }
}
DEV float llc_poll_f32(const float* p) {
  while (true) {
    float r;
    asm volatile("global_load_dword %0, %1, off sc0 sc1\n\ts_waitcnt vmcnt(0)"
                 : "=v"(r) : "v"(p) : "memory");
    if (__all(__builtin_bit_cast(unsigned, r) != 0xFFFFFFFFu)) return r;
    __builtin_amdgcn_s_sleep(1);
  }
}

// swizzled LDS addr for [128][64] bf16 tiles: byte ^= (row&7)<<4 — bijective per
// row; fragment reads conflict-free (verified R10-R14)
DEV bf16* swz(bf16* base, int row, int colbyte) {
  return (bf16*)((char*)base + row * 128 + (colbyte ^ ((row & 7) << 4)));
}

// ---------------- embedding gather -> bf16, layout [T][B][256] ------------------
__global__ void embed_gather(const int* __restrict__ ids, const float* __restrict__ emb,
                             bf16* __restrict__ out, int rows, int ids_stride) {
  long total = (long)rows * 64;  // 4 elems per item
  long stride = (long)gridDim.x * blockDim.x;
  for (long i = (long)blockIdx.x * blockDim.x + threadIdx.x; i < total; i += stride) {
    int row = (int)(i >> 6);   // row = t*32 + b
    int e = ((int)i & 63) * 4;
    int b = row & 31;
    int t = row >> 5;
    int id = ids[b * ids_stride + t];
    f32x4 v = *(const f32x4*)(emb + (long)id * 256 + e);
    short4v o;
#pragma unroll
    for (int j = 0; j < 4; ++j) o[j] = (short)f2bf(v[j]);
    *(short4v*)((short*)out + (long)row * 256 + e) = o;
  }
}

// ---------------- affine GEMM: out[b*64+t+1] = YD1[t*32+b] @ aff_W^T + affb -----
// 128x128 tile, swizzled LDS, k-step register prefetch (structure verified
// R12-R14). R15 changes:
//  * W read directly as fp32 and converted in staging (convert_all deleted —
//    fp32-staging path verified R1-R4 in gemm_fb; swizzle orthogonal).
//  * XCD-aware stripe mapping: ns = (b&7) + 8*(b>>7), mt = (b>>3)&15 — the 16
//    row-tiles of one W stripe stay on one XCD (heuristic b%8->XCD; perf-only),
//    so each stripe lives in a single L2 (~4 MB/XCD) instead of 8 copies.
//  * grid 4096 (8 xcd x 16 mt x 32 q); ns >= 250 blocks exit.
// mt==0 blocks zero out[:,0,:] for their column stripe (R13/R14-verified).
__launch_bounds__(256)
__global__ void gemm_aff(const bf16* __restrict__ Ag, const float* __restrict__ Wf,
                         const float* __restrict__ affb, float* __restrict__ out) {
  __shared__ __align__(16) bf16 As[128 * 64];
  __shared__ __align__(16) bf16 Bs[128 * 64];
  int b = blockIdx.x;
  int ns = (b & 7) + 8 * (b >> 7);
  int mt = (b >> 3) & 15;
  if (ns >= 250) return;
  long m0 = (long)mt * 128, gn0 = (long)ns * 128;
  int tid = threadIdx.x;
  int lane = tid & 63, wave = tid >> 6;
  int wm = wave & 1, wn = wave >> 1;
  int fl = lane & 15, fg = lane >> 4;

  if (mt == 0) {  // zero out[:, 0, gn0:gn0+128): rows b*64, b=0..31
    f32x4 z{};
#pragma unroll
    for (int idx = 0; idx < 4; ++idx) {
      int i = idx * 256 + tid;       // 1024 f32x4 chunks
      int r = i >> 5, c4 = i & 31;   // row b=r, col chunk c4
      *(f32x4*)(out + (long)r * 64 * 32000 + gn0 + c4 * 4) = z;
    }
  }

  f32x4 acc[4][4] = {};
  bf16x8 areg[4];
  f32x4 wv0[4], wv1[4];
  int rowv[4], colv[4];
#pragma unroll
  for (int i = 0; i < 4; ++i) {
    int e = (i * 256 + tid) * 8;
    rowv[i] = e >> 6; colv[i] = e & 63;
    long ar = m0 + rowv[i]; if (ar >= 2016) ar = 2015;
    g_load16(&areg[i], Ag + ar * 512 + colv[i]);
    const float* p = Wf + (gn0 + rowv[i]) * 512l + colv[i];
    wv0[i] = *(const f32x4*)p;
    wv1[i] = *(const f32x4*)(p + 4);
  }
  for (int k0 = 0; k0 < 512; k0 += 64) {
    asm volatile("s_waitcnt vmcnt(0)" ::: "memory");  // this k-step's loads in
    __syncthreads();   // previous MFMA done reading LDS
#pragma unroll
    for (int i = 0; i < 4; ++i) {
      *(bf16x8*)swz(As, rowv[i], colv[i] * 2) = areg[i];
      short8v o;
#pragma unroll
      for (int j = 0; j < 4; ++j) {
        o[j] = (short)f2bf(wv0[i][j]);
        o[j + 4] = (short)f2bf(wv1[i][j]);
      }
      *(short8v*)swz(Bs, rowv[i], colv[i] * 2) = o;
    }
    __syncthreads();
    if (k0 + 64 < 512) {  // prefetch next k-step under the MFMAs
#pragma unroll
      for (int i = 0; i < 4; ++i) {
        long ar = m0 + rowv[i]; if (ar >= 2016) ar = 2015;
        g_load16(&areg[i], Ag + ar * 512 + (k0 + 64) + colv[i]);
        const float* p = Wf + (gn0 + rowv[i]) * 512l + (k0 + 64) + colv[i];
        wv0[i] = *(const f32x4*)p;
        wv1[i] = *(const f32x4*)(p + 4);
      }
    }
#pragma unroll
    for (int kt = 0; kt < 2; ++kt) {
      bf16x8 af[4], bfr[4];
#pragma unroll
      for (int x = 0; x < 4; ++x)
        af[x] = *(const bf16x8*)swz(As, wm * 64 + x * 16 + fl, (kt * 32 + fg * 8) * 2);
#pragma unroll
      for (int x = 0; x < 4; ++x)
        bfr[x] = *(const bf16x8*)swz(Bs, wn * 64 + x * 16 + fl, (kt * 32 + fg * 8) * 2);
#pragma unroll
      for (int mi = 0; mi < 4; ++mi)
#pragma unroll
        for (int ni = 0; ni < 4; ++ni)
          acc[mi][ni] = mfma16(af[mi], bfr[ni], acc[mi][ni]);
    }
  }
#pragma unroll
  for (int mi = 0; mi < 4; ++mi)
#pragma unroll
    for (int ni = 0; ni < 4; ++ni)
#pragma unroll
      for (int r = 0; r < 4; ++r) {
        long row = m0 + wm * 64 + mi * 16 + fg * 4 + r;
        long col = gn0 + wn * 64 + ni * 16 + fl;
        if (row < 2016) {
          float v = acc[mi][ni][r] + affb[col];
          long orow = (long)(row & 31) * 64 + (row >> 5) + 1;  // b*64 + t + 1
          out[orow * 32000 + col] = v;
        }
      }
}

// ---------------- fused 4-layer dataflow LSTM (cooperative, 256 blocks) ---------
// t-loop / sentinel protocol BYTE-IDENTICAL to R12/R14 (best: 474 us). R15:
// weight fragments are converted fp32->bf16 IN-KERNEL at startup (one-time,
// same f2bf RNE bits as convert_all produced — convert_all deleted).
struct FusedParams {
  const float* wih[4]; const float* whh[4];
  const float* bih[4]; const float* bhh[4];
  const bf16* x[4];       // XE, YE0, XD, YD0
  bf16* y[4];             // YE0, YE1, YD0, YD1
  const bf16* hinit[4];   // ZH, ZH, YE0+63*32*512, YE1+63*32*512
  const float* cinit[4];  // ZC, ZC, CE0, CE1
  float* cfin[4];         // CE0, CE1, CD, CD2
};

__launch_bounds__(256)
__global__ void lstm_fused(FusedParams P) {
  __shared__ float part[4][32][33];
  __shared__ __align__(16) unsigned short h_sh[32][8];
  const int tid = threadIdx.x;
  const int lane = tid & 63, wave = tid >> 6;
  const int fl = lane & 15, fg = lane >> 4;
  const int l = blockIdx.x >> 6;
  const int slc = blockIdx.x & 63;
  const int n0 = slc * 8;
  const int b_t = tid & 31, d_t = tid >> 5;
  const int T = (l < 2) ? 64 : 63;
  const int Kx = (l & 1) ? 512 : 256;
  const int xspan = Kx >> 2;   // per-wave x span: 64 or 128
  const int ktx = xspan >> 5;  // 2 or 4
  const float* __restrict__ WihF = P.wih[l];
  const float* __restrict__ WhhF = P.whh[l];
  const bf16* __restrict__ X = P.x[l];
  bf16* __restrict__ Y = P.y[l];
  const bf16* __restrict__ Hinit = P.hinit[l];

  float bsum[4];
#pragma unroll
  for (int gi = 0; gi < 4; ++gi)
    bsum[gi] = P.bih[l][gi * 512 + n0 + d_t] + P.bhh[l][gi * 512 + n0 + d_t];

  // weight fragments: convert fp32 -> bf16 straight into registers (one-time)
  // gate-col j = nt*16+fl -> (gate j>>3, dim j&7)
  bf16x8 wfx[2][4], wfh[2][4];
#pragma unroll
  for (int nt = 0; nt < 2; ++nt) {
    int j = nt * 16 + fl;
    long row = (long)(j >> 3) * 512 + n0 + (j & 7);
#pragma unroll
    for (int kt = 0; kt < 4; ++kt) {
      if (kt < ktx)
        wfx[nt][kt] = cvt8(WihF + row * (long)Kx + wave * xspan + kt * 32 + fg * 8);
      wfh[nt][kt] = cvt8(WhhF + row * 512l + wave * 128 + kt * 32 + fg * 8);
    }
  }
  float c = 0.f;

  for (int t = 0; t < T; ++t) {
    const bf16* xb = X + (long)t * 32 * Kx;
    f32x4 acc[2][2] = {};
    if (l & 1) {
      // x = producer layer's h at step t: data-poll paces the pipeline
      bf16x8 xa0[4], xa1[4];
      poll_slab(xb, fl, wave * 128 + fg * 8, xa0, xa1);
#pragma unroll
      for (int kt = 0; kt < 4; ++kt) {
        acc[0][0] = mfma16(xa0[kt], wfx[0][kt], acc[0][0]);
        acc[0][1] = mfma16(xa0[kt], wfx[1][kt], acc[0][1]);
        acc[1][0] = mfma16(xa1[kt], wfx[0][kt], acc[1][0]);
        acc[1][1] = mfma16(xa1[kt], wfx[1][kt], acc[1][1]);
      }
    } else {
      // XE/XD precomputed in a prior dispatch: normal cached loads
      bf16x8 xa0[2], xa1[2];
#pragma unroll
      for (int kt = 0; kt < 2; ++kt) {
        int k = wave * xspan + kt * 32 + fg * 8;
        xa0[kt] = *(const bf16x8*)(xb + (long)fl * Kx + k);
        xa1[kt] = *(const bf16x8*)(xb + (long)(fl + 16) * Kx + k);
      }
#pragma unroll
      for (int kt = 0; kt < 2; ++kt) {
        acc[0][0] = mfma16(xa0[kt], wfx[0][kt], acc[0][0]);
        acc[0][1] = mfma16(xa0[kt], wfx[1][kt], acc[0][1]);
        acc[1][0] = mfma16(xa1[kt], wfx[0][kt], acc[1][0]);
        acc[1][1] = mfma16(xa1[kt], wfx[1][kt], acc[1][1]);
      }
    }

    // ---- h phase: data-poll own/init h slab (the pacing dependency) ----
    const bf16* hb = (t == 0) ? Hinit : (Y + (long)(t - 1) * 32 * 512);
    bf16x8 ha0[4], ha1[4];
    poll_slab(hb, fl, wave * 128 + fg * 8, ha0, ha1);
    if (t == 0) c = llc_poll_f32(P.cinit[l] + (long)b_t * 512 + n0 + d_t);
#pragma unroll
    for (int kt = 0; kt < 4; ++kt) {
      acc[0][0] = mfma16(ha0[kt], wfh[0][kt], acc[0][0]);
      acc[0][1] = mfma16(ha0[kt], wfh[1][kt], acc[0][1]);
      acc[1][0] = mfma16(ha1[kt], wfh[0][kt], acc[1][0]);
      acc[1][1] = mfma16(ha1[kt], wfh[1][kt], acc[1][1]);
    }
#pragma unroll
    for (int mt = 0; mt < 2; ++mt)
#pragma unroll
      for (int nt = 0; nt < 2; ++nt)
#pragma unroll
        for (int r = 0; r < 4; ++r)
          part[wave][mt * 16 + fg * 4 + r][nt * 16 + fl] = acc[mt][nt][r];
    __syncthreads();

    // reduce 4 K-partials + activations; thread (b_t, d_t)
    float g4[4];
#pragma unroll
    for (int gi = 0; gi < 4; ++gi) {
      int j = gi * 8 + d_t;
      g4[gi] = part[0][b_t][j] + part[1][b_t][j] + part[2][b_t][j] + part[3][b_t][j] +
               bsum[gi];
    }
    float ig = 1.f / (1.f + __expf(-g4[0]));
    float ff = 1.f / (1.f + __expf(-g4[1]));
    float gg = tanhf(g4[2]);
    float og = 1.f / (1.f + __expf(-g4[3]));
    c = ff * c + ig * gg;
    float h = og * tanhf(c);
    h_sh[b_t][d_t] = f2bf(h);
    if (t == T - 1)
      llc_store_f32(P.cfin[l] + (long)b_t * 512 + n0 + d_t, c);  // data-polled
    __syncthreads();  // h_sh complete; also part[] reuse guard
    // wave 0 publishes coalesced, NO drain/flag (data IS the flag);
    // waves 1-3 run ahead into next step immediately
    if (wave == 0 && lane < 32)
      llc_store16((unsigned short*)Y + ((long)t * 32 + lane) * 512 + n0,
                  *(const short8v*)(&h_sh[lane][0]));
  }
}

extern "C" void kernel_launch(void* const* d_in, const int* in_sizes, int n_in,
                              void* d_out, int out_size, void* d_ws, size_t ws_size,
                              hipStream_t stream) {
  (void)in_sizes; (void)n_in; (void)out_size; (void)ws_size;
  const int*   source   = (const int*)d_in[0];
  const int*   target   = (const int*)d_in[1];
  const float* enc_emb  = (const float*)d_in[2];
  const float* enc_Wih0 = (const float*)d_in[3];
  const float* enc_Whh0 = (const float*)d_in[4];
  const float* enc_bih0 = (const float*)d_in[5];
  const float* enc_bhh0 = (const float*)d_in[6];
  const float* enc_Wih1 = (const float*)d_in[7];
  const float* enc_Whh1 = (const float*)d_in[8];
  const float* enc_bih1 = (const float*)d_in[9];
  const float* enc_bhh1 = (const float*)d_in[10];
  const float* dec_emb  = (const float*)d_in[11];
  const float* dec_Wih0 = (const float*)d_in[12];
  const float* dec_Whh0 = (const float*)d_in[13];
  const float* dec_bih0 = (const float*)d_in[14];
  const float* dec_bhh0 = (const float*)d_in[15];
  const float* dec_Wih1 = (const float*)d_in[16];
  const float* dec_Whh1 = (const float*)d_in[17];
  const float* dec_bih1 = (const float*)d_in[18];
  const float* dec_bhh1 = (const float*)d_in[19];
  const float* aff_W    = (const float*)d_in[20];
  const float* aff_b    = (const float*)d_in[21];
  float* out = (float*)d_out;

  size_t off = 0;
  auto alc = [&](size_t bytes) {
    char* p = (char*)d_ws + off;
    off += (bytes + 255) & ~(size_t)255;
    return (void*)p;
  };
  // zero region (valid-zero h/c inits)
  bf16*  ZH  = (bf16*)alc(32 * 512 * 2);
  float* ZC  = (float*)alc(32 * 512 * 4);
  size_t zero_span = off;
  // poison region (data-is-flag buffers, re-poisoned 0xFF every launch)
  size_t poison_begin = off;
  float* CE0 = (float*)alc(32 * 512 * 4);
  float* CE1 = (float*)alc(32 * 512 * 4);
  bf16*  YE0 = (bf16*)alc((size_t)2048 * 512 * 2);   // [64][32][512]
  bf16*  YE1 = (bf16*)alc((size_t)2048 * 512 * 2);
  bf16*  YD0 = (bf16*)alc((size_t)2016 * 512 * 2);   // [63][32][512]
  bf16*  YD1 = (bf16*)alc((size_t)2016 * 512 * 2);
  size_t poison_end = off;
  // plain scratch
  float* CD  = (float*)alc(32 * 512 * 4);
  float* CD2 = (float*)alc(32 * 512 * 4);
  bf16*  XE  = (bf16*)alc((size_t)2048 * 256 * 2);   // [64][32][256]
  bf16*  XD  = (bf16*)alc((size_t)2016 * 256 * 2);   // [63][32][256]

  hipMemsetAsync(d_ws, 0, zero_span, stream);
  hipMemsetAsync((char*)d_ws + poison_begin, 0xFF, poison_end - poison_begin, stream);

  embed_gather<<<dim3(512), dim3(256), 0, stream>>>(source, enc_emb, XE, 2048, 64);
  embed_gather<<<dim3(512), dim3(256), 0, stream>>>(target, dec_emb, XD, 2016, 64);

  FusedParams P;
  P.wih[0] = enc_Wih0; P.whh[0] = enc_Whh0; P.bih[0] = enc_bih0; P.bhh[0] = enc_bhh0;
  P.wih[1] = enc_Wih1; P.whh[1] = enc_Whh1; P.bih[1] = enc_bih1; P.bhh[1] = enc_bhh1;
  P.wih[2] = dec_Wih0; P.whh[2] = dec_Whh0; P.bih[2] = dec_bih0; P.bhh[2] = dec_bhh0;
  P.wih[3] = dec_Wih1; P.whh[3] = dec_Whh1; P.bih[3] = dec_bih1; P.bhh[3] = dec_bhh1;
  P.x[0] = XE;  P.x[1] = YE0; P.x[2] = XD;  P.x[3] = YD0;
  P.y[0] = YE0; P.y[1] = YE1; P.y[2] = YD0; P.y[3] = YD1;
  P.hinit[0] = ZH; P.hinit[1] = ZH;
  P.hinit[2] = YE0 + (size_t)63 * 32 * 512;
  P.hinit[3] = YE1 + (size_t)63 * 32 * 512;
  P.cinit[0] = ZC;  P.cinit[1] = ZC;  P.cinit[2] = CE0; P.cinit[3] = CE1;
  P.cfin[0]  = CE0; P.cfin[1]  = CE1; P.cfin[2]  = CD;  P.cfin[3]  = CD2;
  void* args[1] = {&P};
  hipLaunchCooperativeKernel((void*)lstm_fused, dim3(256), dim3(256), args, 0, stream);

  // out[:,0,:]=0 + out[:,1:,:] = d1 @ aff_W^T + aff_b (W converted in staging)
  gemm_aff<<<dim3(4096), dim3(256), 0, stream>>>(YD1, aff_W, aff_b, out);
}

// Round 16
// 639.467 us; speedup vs baseline: 1.1021x; 1.1021x over previous
//
#include <hip/hip_runtime.h>
#include <hip/hip_bf16.h>

using bf16 = __hip_bfloat16;
typedef __bf16 bf16x8 __attribute__((ext_vector_type(8)));
typedef float f32x4 __attribute__((ext_vector_type(4)));
typedef int i32x4 __attribute__((ext_vector_type(4)));
typedef short short4v __attribute__((ext_vector_type(4)));
typedef short short8v __attribute__((ext_vector_type(8)));

#define DEV __device__ __forceinline__

// B=32, S=64, T=64 (dec 63), V=32000, E=256, H=512, 4H=2048

DEV unsigned short f2bf(float f) {  // RNE float->bf16
  unsigned u = __builtin_bit_cast(unsigned, f);
  u = (u + 0x7fffu + ((u >> 16) & 1u)) >> 16;
  return (unsigned short)u;
}

DEV f32x4 mfma16(bf16x8 a, bf16x8 b, f32x4 c) {
  return __builtin_amdgcn_mfma_f32_16x16x32_bf16(a, b, c, 0, 0, 0);
}

// ---- LLC-coherent (bypass L1+L2) access helpers ------------------------------
DEV void llc_load16(bf16x8* dst, const bf16* p) {  // issue only; caller waits vmcnt
  i32x4 r;
  asm volatile("global_load_dwordx4 %0, %1, off sc0 sc1" : "=v"(r) : "v"(p) : "memory");
  *dst = __builtin_bit_cast(bf16x8, r);
}
DEV void g_load16(bf16x8* dst, const bf16* p) {  // plain (L1/L2-cached), asm-ordered
  i32x4 r;
  asm volatile("global_load_dwordx4 %0, %1, off" : "=v"(r) : "v"(p) : "memory");
  *dst = __builtin_bit_cast(bf16x8, r);
}
DEV void llc_store16(void* p, short8v v) {
  asm volatile("global_store_dwordx4 %0, %1, off sc0 sc1"
               :: "v"(p), "v"(__builtin_bit_cast(i32x4, v)) : "memory");
}
DEV void llc_store_f32(float* p, float v) {
  asm volatile("global_store_dword %0, %1, off sc0 sc1" :: "v"(p), "v"(v) : "memory");
}
DEV bool valid16(bf16x8 v) {  // no dword still holds the 0xFFFFFFFF poison
  i32x4 u = __builtin_bit_cast(i32x4, v);
  return (u[0] != -1) && (u[1] != -1) && (u[2] != -1) && (u[3] != -1);
}

// Data-is-flag slab read with cheap wait loop (R12-verified ordering:
// issue AFTER the x phase — pre-issuing before it regressed 2x in R13).
// 1) opportunistic full load + validate (ready case: 1 LLC RTT)
// 2) not ready: sentinel loop — 4 dwords/lane (one per producer chunk) only
// 3) full reload + validate (rare path)
DEV void poll_slab(const bf16* base, int fl, int koff, bf16x8 a0[4], bf16x8 a1[4]) {
  const bf16* r0 = base + (long)fl * 512 + koff;
  const bf16* r1 = base + (long)(fl + 16) * 512 + koff;
#pragma unroll
  for (int kt = 0; kt < 4; ++kt) {
    llc_load16(&a0[kt], r0 + kt * 32);
    llc_load16(&a1[kt], r1 + kt * 32);
  }
  asm volatile("s_waitcnt vmcnt(0)" ::: "memory");
  {
    bool ok = true;
#pragma unroll
    for (int kt = 0; kt < 4; ++kt) ok = ok && valid16(a0[kt]) && valid16(a1[kt]);
    if (__all(ok)) return;
  }
  // sentinel wait: 1 dword per producer chunk (8x less traffic than full slab)
  while (true) {
    unsigned s0, s1, s2, s3;
    asm volatile(
        "global_load_dword %0, %4, off sc0 sc1\n\t"
        "global_load_dword %1, %5, off sc0 sc1\n\t"
        "global_load_dword %2, %6, off sc0 sc1\n\t"
        "global_load_dword %3, %7, off sc0 sc1\n\t"
        "s_waitcnt vmcnt(0)"
        : "=v"(s0), "=v"(s1), "=v"(s2), "=v"(s3)
        : "v"(r0), "v"(r0 + 32), "v"(r0 + 64), "v"(r0 + 96)
        : "memory");
    bool ok = (s0 != 0xFFFFFFFFu) & (s1 != 0xFFFFFFFFu) & (s2 != 0xFFFFFFFFu) &
              (s3 != 0xFFFFFFFFu);
    if (__all(ok)) break;
    __builtin_amdgcn_s_sleep(1);
  }
  // full reload + validate (covers row fl+16 and every dword)
  while (true) {
#pragma unroll
    for (int kt = 0; kt < 4; ++kt) {
      llc_load16(&a0[kt], r0 + kt * 32);
      llc_load16(&a1[kt], r1 + kt * 32);
    }
    asm volatile("s_waitcnt vmcnt(0)" ::: "memory");
    bool ok = true;
#pragma unroll
    for (int kt = 0; kt < 4; ++kt) ok = ok && valid16(a0[kt]) && valid16(a1[kt]);
    if (__all(ok)) break;
    __builtin_amdgcn_s_sleep(1);
  }
}
DEV float llc_poll_f32(const float* p) {
  while (true) {
    float r;
    asm volatile("global_load_dword %0, %1, off sc0 sc1\n\ts_waitcnt vmcnt(0)"
                 : "=v"(r) : "v"(p) : "memory");
    if (__all(__builtin_bit_cast(unsigned, r) != 0xFFFFFFFFu)) return r;
    __builtin_amdgcn_s_sleep(1);
  }
}

// swizzled LDS addr for [128][64] bf16 tiles: byte ^= (row&7)<<4 — bijective per
// row; fragment reads conflict-free (verified R10-R14)
DEV bf16* swz(bf16* base, int row, int colbyte) {
  return (bf16*)((char*)base + row * 128 + (colbyte ^ ((row & 7) << 4)));
}

// ---------------- fp32 -> bf16 weight conversion --------------------------------
struct ConvJobs {
  const float* src[9];
  bf16* dst[9];
  int n[9];
  int cnt;
};

__global__ void convert_all(ConvJobs jobs) {
  long base = (long)blockIdx.x * blockDim.x + threadIdx.x;
  long stride = (long)gridDim.x * blockDim.x;
  for (int ji = 0; ji < jobs.cnt; ++ji) {
    const float* s = jobs.src[ji];
    bf16* d = jobs.dst[ji];
    long n4 = (long)jobs.n[ji] >> 2;
    for (long i = base; i < n4; i += stride) {
      f32x4 v = *(const f32x4*)(s + i * 4);
      short4v o;
#pragma unroll
      for (int j = 0; j < 4; ++j) o[j] = (short)f2bf(v[j]);
      *(short4v*)((short*)d + i * 4) = o;
    }
  }
}

// ---------------- embedding gather -> bf16, layout [T][B][256] ------------------
__global__ void embed_gather(const int* __restrict__ ids, const float* __restrict__ emb,
                             bf16* __restrict__ out, int rows, int ids_stride) {
  long total = (long)rows * 64;  // 4 elems per item
  long stride = (long)gridDim.x * blockDim.x;
  for (long i = (long)blockIdx.x * blockDim.x + threadIdx.x; i < total; i += stride) {
    int row = (int)(i >> 6);   // row = t*32 + b
    int e = ((int)i & 63) * 4;
    int b = row & 31;
    int t = row >> 5;
    int id = ids[b * ids_stride + t];
    f32x4 v = *(const f32x4*)(emb + (long)id * 256 + e);
    short4v o;
#pragma unroll
    for (int j = 0; j < 4; ++j) o[j] = (short)f2bf(v[j]);
    *(short4v*)((short*)out + (long)row * 256 + e) = o;
  }
}

// ---------------- zero out[:, 0, :] (fallback path only) ------------------------
__global__ void zero_t0(float* __restrict__ out) {
  long total = 32l * 8000;  // float4 per item
  long stride = (long)gridDim.x * blockDim.x;
  f32x4 z{};
  for (long i = (long)blockIdx.x * blockDim.x + threadIdx.x; i < total; i += stride) {
    long b = i / 8000;
    long v = i - b * 8000;
    *(f32x4*)(out + b * 64 * 32000 + v * 4) = z;
  }
}

// ---------------- affine GEMM: out[b*64+t+1] = YD1[t*32+b] @ WAFF^T + affb ------
// 128x128 tile, swizzled LDS, k-step register prefetch (R12-R14-verified). A
// plain loads (cross-dispatch coherence via HSA barrier, R14-verified neutral
// vs sc0 sc1 — kept plain). W bf16 preconverted, plain (L2-sticky; mt-fastest
// block order keeps concurrent blocks on shared W stripes). mt==0 blocks zero
// out[:,0,:] for their column stripe (replaces the zero_t0 launch).
__launch_bounds__(256)
__global__ void gemm_aff(const bf16* __restrict__ Ag, const bf16* __restrict__ Wg,
                         const float* __restrict__ affb, float* __restrict__ out) {
  __shared__ __align__(16) bf16 As[128 * 64];
  __shared__ __align__(16) bf16 Bs[128 * 64];
  int mt = blockIdx.x & 15;    // m fastest: concurrent blocks share W stripes
  int ns = blockIdx.x >> 4;
  long m0 = (long)mt * 128, gn0 = (long)ns * 128;
  int tid = threadIdx.x;
  int lane = tid & 63, wave = tid >> 6;
  int wm = wave & 1, wn = wave >> 1;
  int fl = lane & 15, fg = lane >> 4;

  if (mt == 0) {  // zero out[:, 0, gn0:gn0+128): rows b*64, b=0..31
    f32x4 z{};
#pragma unroll
    for (int idx = 0; idx < 4; ++idx) {
      int i = idx * 256 + tid;       // 1024 f32x4 chunks
      int r = i >> 5, c4 = i & 31;   // row b=r, col chunk c4
      *(f32x4*)(out + (long)r * 64 * 32000 + gn0 + c4 * 4) = z;
    }
  }

  f32x4 acc[4][4] = {};
  bf16x8 areg[4], wreg[4];
  int rowv[4], colv[4];
#pragma unroll
  for (int i = 0; i < 4; ++i) {
    int e = (i * 256 + tid) * 8;
    rowv[i] = e >> 6; colv[i] = e & 63;
    long ar = m0 + rowv[i]; if (ar >= 2016) ar = 2015;
    g_load16(&areg[i], Ag + ar * 512 + colv[i]);
    g_load16(&wreg[i], Wg + (gn0 + rowv[i]) * 512 + colv[i]);
  }
  for (int k0 = 0; k0 < 512; k0 += 64) {
    asm volatile("s_waitcnt vmcnt(0)" ::: "memory");  // this k-step's loads in
    __syncthreads();   // previous MFMA done reading LDS
#pragma unroll
    for (int i = 0; i < 4; ++i) {
      *(bf16x8*)swz(As, rowv[i], colv[i] * 2) = areg[i];
      *(bf16x8*)swz(Bs, rowv[i], colv[i] * 2) = wreg[i];
    }
    __syncthreads();
    if (k0 + 64 < 512) {  // prefetch next k-step under the MFMAs
#pragma unroll
      for (int i = 0; i < 4; ++i) {
        long ar = m0 + rowv[i]; if (ar >= 2016) ar = 2015;
        g_load16(&areg[i], Ag + ar * 512 + (k0 + 64) + colv[i]);
        g_load16(&wreg[i], Wg + (gn0 + rowv[i]) * 512 + (k0 + 64) + colv[i]);
      }
    }
#pragma unroll
    for (int kt = 0; kt < 2; ++kt) {
      bf16x8 af[4], bfr[4];
#pragma unroll
      for (int x = 0; x < 4; ++x)
        af[x] = *(const bf16x8*)swz(As, wm * 64 + x * 16 + fl, (kt * 32 + fg * 8) * 2);
#pragma unroll
      for (int x = 0; x < 4; ++x)
        bfr[x] = *(const bf16x8*)swz(Bs, wn * 64 + x * 16 + fl, (kt * 32 + fg * 8) * 2);
#pragma unroll
      for (int mi = 0; mi < 4; ++mi)
#pragma unroll
        for (int ni = 0; ni < 4; ++ni)
          acc[mi][ni] = mfma16(af[mi], bfr[ni], acc[mi][ni]);
    }
  }
#pragma unroll
  for (int mi = 0; mi < 4; ++mi)
#pragma unroll
    for (int ni = 0; ni < 4; ++ni)
#pragma unroll
      for (int r = 0; r < 4; ++r) {
        long row = m0 + wm * 64 + mi * 16 + fg * 4 + r;
        long col = gn0 + wn * 64 + ni * 16 + fl;
        if (row < 2016) {
          float v = acc[mi][ni][r] + affb[col];
          long orow = (long)(row & 31) * 64 + (row >> 5) + 1;  // b*64 + t + 1
          out[orow * 32000 + col] = v;
        }
      }
}

// ---------------- fallback GEMM (fp32 W in-staging, ws too small for WAFF) ------
__launch_bounds__(256)
__global__ void gemm_fb(const bf16* __restrict__ A, const float* __restrict__ Wf,
                        const float* __restrict__ bias1, float* __restrict__ C,
                        int M, int N, int K) {
  __shared__ __align__(16) bf16 As[128][64];
  __shared__ __align__(16) bf16 Bs[128][64];
  int nm = (M + 127) >> 7;
  int mt_blk = blockIdx.x % nm;
  int nt_blk = blockIdx.x / nm;
  long m0 = (long)mt_blk * 128, n0 = (long)nt_blk * 128;
  int tid = threadIdx.x;
  int lane = tid & 63, wave = tid >> 6;
  int wm = wave & 1, wn = wave >> 1;
  int fl = lane & 15, fg = lane >> 4;
  f32x4 acc[4][4] = {};
  for (int k0 = 0; k0 < K; k0 += 64) {
    __syncthreads();
#pragma unroll
    for (int i = 0; i < 4; ++i) {
      int e = (i * 256 + tid) * 8;
      int row = e >> 6, col = e & 63;
      long ar = m0 + row; if (ar >= M) ar = M - 1;
      *(bf16x8*)(&As[row][col]) = *(const bf16x8*)(A + ar * (long)K + k0 + col);
      long br = n0 + row; if (br >= N) br = N - 1;
      const float* p = Wf + br * (long)K + k0 + col;
      f32x4 v0 = *(const f32x4*)p, v1 = *(const f32x4*)(p + 4);
      short8v o;
#pragma unroll
      for (int j = 0; j < 4; ++j) { o[j] = (short)f2bf(v0[j]); o[j + 4] = (short)f2bf(v1[j]); }
      *(short8v*)(&Bs[row][col]) = o;
    }
    __syncthreads();
#pragma unroll
    for (int kt = 0; kt < 2; ++kt) {
      bf16x8 af[4], bfr[4];
#pragma unroll
      for (int x = 0; x < 4; ++x)
        af[x] = *(const bf16x8*)(&As[wm * 64 + x * 16 + fl][kt * 32 + fg * 8]);
#pragma unroll
      for (int x = 0; x < 4; ++x)
        bfr[x] = *(const bf16x8*)(&Bs[wn * 64 + x * 16 + fl][kt * 32 + fg * 8]);
#pragma unroll
      for (int mi = 0; mi < 4; ++mi)
#pragma unroll
        for (int ni = 0; ni < 4; ++ni)
          acc[mi][ni] = mfma16(af[mi], bfr[ni], acc[mi][ni]);
    }
  }
#pragma unroll
  for (int mi = 0; mi < 4; ++mi)
#pragma unroll
    for (int ni = 0; ni < 4; ++ni)
#pragma unroll
      for (int r = 0; r < 4; ++r) {
        long row = m0 + wm * 64 + mi * 16 + fg * 4 + r;
        long col = n0 + wn * 64 + ni * 16 + fl;
        if (row < M && col < N) {
          float v = acc[mi][ni][r] + bias1[col];
          long orow = (long)(row & 31) * 64 + (row >> 5) + 1;
          C[orow * (long)N + col] = v;
        }
      }
}

// ---------------- fused 4-layer dataflow LSTM (cooperative, 256 blocks) ---------
// BYTE-IDENTICAL to R12/R14 (best measured: 474 us, reproduced 3x). Block
// (l, slc): layer l = blockIdx>>6, hidden slice n0 = (blockIdx&63)*8. Sentinel
// data-is-flag sync: h/c buffers poison-filled (0xFF) per launch; producers
// publish coalesced 32x16B straight after the barrier (no drain/flag);
// consumers do opportunistic slab load + poison-validate with a cheap 4-dword
// sentinel fallback. h slab issued AFTER the x phase (R13's pre-issue regressed
// 2x: loads landed before the producer published -> guaranteed fallback path).
struct FusedParams {
  const bf16* wih[4]; const bf16* whh[4];
  const float* bih[4]; const float* bhh[4];
  const bf16* x[4];       // XE, YE0, XD, YD0
  bf16* y[4];             // YE0, YE1, YD0, YD1
  const bf16* hinit[4];   // ZH, ZH, YE0+63*32*512, YE1+63*32*512
  const float* cinit[4];  // ZC, ZC, CE0, CE1
  float* cfin[4];         // CE0, CE1, CD, CD2
};

__launch_bounds__(256)
__global__ void lstm_fused(FusedParams P) {
  __shared__ float part[4][32][33];
  __shared__ __align__(16) unsigned short h_sh[32][8];
  const int tid = threadIdx.x;
  const int lane = tid & 63, wave = tid >> 6;
  const int fl = lane & 15, fg = lane >> 4;
  const int l = blockIdx.x >> 6;
  const int slc = blockIdx.x & 63;
  const int n0 = slc * 8;
  const int b_t = tid & 31, d_t = tid >> 5;
  const int T = (l < 2) ? 64 : 63;
  const int Kx = (l & 1) ? 512 : 256;
  const int xspan = Kx >> 2;   // per-wave x span: 64 or 128
  const int ktx = xspan >> 5;  // 2 or 4
  const bf16* __restrict__ Wih = P.wih[l];
  const bf16* __restrict__ Whh = P.whh[l];
  const bf16* __restrict__ X = P.x[l];
  bf16* __restrict__ Y = P.y[l];
  const bf16* __restrict__ Hinit = P.hinit[l];

  float bsum[4];
#pragma unroll
  for (int gi = 0; gi < 4; ++gi)
    bsum[gi] = P.bih[l][gi * 512 + n0 + d_t] + P.bhh[l][gi * 512 + n0 + d_t];

  // weight fragments in registers: gate-col j = nt*16+fl -> (gate j>>3, dim j&7)
  bf16x8 wfx[2][4], wfh[2][4];
#pragma unroll
  for (int nt = 0; nt < 2; ++nt) {
    int j = nt * 16 + fl;
    long row = (long)(j >> 3) * 512 + n0 + (j & 7);
#pragma unroll
    for (int kt = 0; kt < 4; ++kt) {
      if (kt < ktx)
        wfx[nt][kt] =
            *(const bf16x8*)(Wih + row * (long)Kx + wave * xspan + kt * 32 + fg * 8);
      wfh[nt][kt] = *(const bf16x8*)(Whh + row * 512l + wave * 128 + kt * 32 + fg * 8);
    }
  }
  float c = 0.f;

  for (int t = 0; t < T; ++t) {
    const bf16* xb = X + (long)t * 32 * Kx;
    f32x4 acc[2][2] = {};
    if (l & 1) {
      // x = producer layer's h at step t: data-poll paces the pipeline
      bf16x8 xa0[4], xa1[4];
      poll_slab(xb, fl, wave * 128 + fg * 8, xa0, xa1);
#pragma unroll
      for (int kt = 0; kt < 4; ++kt) {
        acc[0][0] = mfma16(xa0[kt], wfx[0][kt], acc[0][0]);
        acc[0][1] = mfma16(xa0[kt], wfx[1][kt], acc[0][1]);
        acc[1][0] = mfma16(xa1[kt], wfx[0][kt], acc[1][0]);
        acc[1][1] = mfma16(xa1[kt], wfx[1][kt], acc[1][1]);
      }
    } else {
      // XE/XD precomputed in a prior dispatch: normal cached loads
      bf16x8 xa0[2], xa1[2];
#pragma unroll
      for (int kt = 0; kt < 2; ++kt) {
        int k = wave * xspan + kt * 32 + fg * 8;
        xa0[kt] = *(const bf16x8*)(xb + (long)fl * Kx + k);
        xa1[kt] = *(const bf16x8*)(xb + (long)(fl + 16) * Kx + k);
      }
#pragma unroll
      for (int kt = 0; kt < 2; ++kt) {
        acc[0][0] = mfma16(xa0[kt], wfx[0][kt], acc[0][0]);
        acc[0][1] = mfma16(xa0[kt], wfx[1][kt], acc[0][1]);
        acc[1][0] = mfma16(xa1[kt], wfx[0][kt], acc[1][0]);
        acc[1][1] = mfma16(xa1[kt], wfx[1][kt], acc[1][1]);
      }
    }

    // ---- h phase: data-poll own/init h slab (the pacing dependency) ----
    const bf16* hb = (t == 0) ? Hinit : (Y + (long)(t - 1) * 32 * 512);
    bf16x8 ha0[4], ha1[4];
    poll_slab(hb, fl, wave * 128 + fg * 8, ha0, ha1);
    if (t == 0) c = llc_poll_f32(P.cinit[l] + (long)b_t * 512 + n0 + d_t);
#pragma unroll
    for (int kt = 0; kt < 4; ++kt) {
      acc[0][0] = mfma16(ha0[kt], wfh[0][kt], acc[0][0]);
      acc[0][1] = mfma16(ha0[kt], wfh[1][kt], acc[0][1]);
      acc[1][0] = mfma16(ha1[kt], wfh[0][kt], acc[1][0]);
      acc[1][1] = mfma16(ha1[kt], wfh[1][kt], acc[1][1]);
    }
#pragma unroll
    for (int mt = 0; mt < 2; ++mt)
#pragma unroll
      for (int nt = 0; nt < 2; ++nt)
#pragma unroll
        for (int r = 0; r < 4; ++r)
          part[wave][mt * 16 + fg * 4 + r][nt * 16 + fl] = acc[mt][nt][r];
    __syncthreads();

    // reduce 4 K-partials + activations; thread (b_t, d_t)
    float g4[4];
#pragma unroll
    for (int gi = 0; gi < 4; ++gi) {
      int j = gi * 8 + d_t;
      g4[gi] = part[0][b_t][j] + part[1][b_t][j] + part[2][b_t][j] + part[3][b_t][j] +
               bsum[gi];
    }
    float ig = 1.f / (1.f + __expf(-g4[0]));
    float ff = 1.f / (1.f + __expf(-g4[1]));
    float gg = tanhf(g4[2]);
    float og = 1.f / (1.f + __expf(-g4[3]));
    c = ff * c + ig * gg;
    float h = og * tanhf(c);
    h_sh[b_t][d_t] = f2bf(h);
    if (t == T - 1)
      llc_store_f32(P.cfin[l] + (long)b_t * 512 + n0 + d_t, c);  // data-polled
    __syncthreads();  // h_sh complete; also part[] reuse guard
    // wave 0 publishes coalesced, NO drain/flag (data IS the flag);
    // waves 1-3 run ahead into next step immediately
    if (wave == 0 && lane < 32)
      llc_store16((unsigned short*)Y + ((long)t * 32 + lane) * 512 + n0,
                  *(const short8v*)(&h_sh[lane][0]));
  }
}

extern "C" void kernel_launch(void* const* d_in, const int* in_sizes, int n_in,
                              void* d_out, int out_size, void* d_ws, size_t ws_size,
                              hipStream_t stream) {
  (void)in_sizes; (void)n_in; (void)out_size;
  const int*   source   = (const int*)d_in[0];
  const int*   target   = (const int*)d_in[1];
  const float* enc_emb  = (const float*)d_in[2];
  const float* enc_Wih0 = (const float*)d_in[3];
  const float* enc_Whh0 = (const float*)d_in[4];
  const float* enc_bih0 = (const float*)d_in[5];
  const float* enc_bhh0 = (const float*)d_in[6];
  const float* enc_Wih1 = (const float*)d_in[7];
  const float* enc_Whh1 = (const float*)d_in[8];
  const float* enc_bih1 = (const float*)d_in[9];
  const float* enc_bhh1 = (const float*)d_in[10];
  const float* dec_emb  = (const float*)d_in[11];
  const float* dec_Wih0 = (const float*)d_in[12];
  const float* dec_Whh0 = (const float*)d_in[13];
  const float* dec_bih0 = (const float*)d_in[14];
  const float* dec_bhh0 = (const float*)d_in[15];
  const float* dec_Wih1 = (const float*)d_in[16];
  const float* dec_Whh1 = (const float*)d_in[17];
  const float* dec_bih1 = (const float*)d_in[18];
  const float* dec_bhh1 = (const float*)d_in[19];
  const float* aff_W    = (const float*)d_in[20];
  const float* aff_b    = (const float*)d_in[21];
  float* out = (float*)d_out;

  size_t off = 0;
  auto alc = [&](size_t bytes) {
    char* p = (char*)d_ws + off;
    off += (bytes + 255) & ~(size_t)255;
    return (void*)p;
  };
  // zero region (valid-zero h/c inits)
  bf16*  ZH  = (bf16*)alc(32 * 512 * 2);
  float* ZC  = (float*)alc(32 * 512 * 4);
  size_t zero_span = off;
  // poison region (data-is-flag buffers, re-poisoned 0xFF every launch)
  size_t poison_begin = off;
  float* CE0 = (float*)alc(32 * 512 * 4);
  float* CE1 = (float*)alc(32 * 512 * 4);
  bf16*  YE0 = (bf16*)alc((size_t)2048 * 512 * 2);   // [64][32][512]
  bf16*  YE1 = (bf16*)alc((size_t)2048 * 512 * 2);
  bf16*  YD0 = (bf16*)alc((size_t)2016 * 512 * 2);   // [63][32][512]
  bf16*  YD1 = (bf16*)alc((size_t)2016 * 512 * 2);
  size_t poison_end = off;
  // plain scratch
  float* CD  = (float*)alc(32 * 512 * 4);
  float* CD2 = (float*)alc(32 * 512 * 4);
  bf16*  XE  = (bf16*)alc((size_t)2048 * 256 * 2);   // [64][32][256]
  bf16*  XD  = (bf16*)alc((size_t)2016 * 256 * 2);   // [63][32][256]
  bf16*  WI0E = (bf16*)alc((size_t)2048 * 256 * 2);
  bf16*  WH0E = (bf16*)alc((size_t)2048 * 512 * 2);
  bf16*  WI1E = (bf16*)alc((size_t)2048 * 512 * 2);
  bf16*  WH1E = (bf16*)alc((size_t)2048 * 512 * 2);
  bf16*  WI0D = (bf16*)alc((size_t)2048 * 256 * 2);
  bf16*  WH0D = (bf16*)alc((size_t)2048 * 512 * 2);
  bf16*  WI1D = (bf16*)alc((size_t)2048 * 512 * 2);
  bf16*  WH1D = (bf16*)alc((size_t)2048 * 512 * 2);
  bf16*  WAFF = (bf16*)alc((size_t)32000 * 512 * 2);  // 32.8 MB, optional
  bool use_waff = (off <= ws_size);

  hipMemsetAsync(d_ws, 0, zero_span, stream);
  hipMemsetAsync((char*)d_ws + poison_begin, 0xFF, poison_end - poison_begin, stream);

  ConvJobs cj;
  cj.src[0] = enc_Wih0; cj.dst[0] = WI0E; cj.n[0] = 2048 * 256;
  cj.src[1] = enc_Whh0; cj.dst[1] = WH0E; cj.n[1] = 2048 * 512;
  cj.src[2] = enc_Wih1; cj.dst[2] = WI1E; cj.n[2] = 2048 * 512;
  cj.src[3] = enc_Whh1; cj.dst[3] = WH1E; cj.n[3] = 2048 * 512;
  cj.src[4] = dec_Wih0; cj.dst[4] = WI0D; cj.n[4] = 2048 * 256;
  cj.src[5] = dec_Whh0; cj.dst[5] = WH0D; cj.n[5] = 2048 * 512;
  cj.src[6] = dec_Wih1; cj.dst[6] = WI1D; cj.n[6] = 2048 * 512;
  cj.src[7] = dec_Whh1; cj.dst[7] = WH1D; cj.n[7] = 2048 * 512;
  cj.cnt = 8;
  if (use_waff) {
    cj.src[8] = aff_W; cj.dst[8] = WAFF; cj.n[8] = 32000 * 512; cj.cnt = 9;
  }
  convert_all<<<dim3(1024), dim3(256), 0, stream>>>(cj);

  embed_gather<<<dim3(512), dim3(256), 0, stream>>>(source, enc_emb, XE, 2048, 64);
  embed_gather<<<dim3(512), dim3(256), 0, stream>>>(target, dec_emb, XD, 2016, 64);
  if (!use_waff) zero_t0<<<dim3(1000), dim3(256), 0, stream>>>(out);

  FusedParams P;
  P.wih[0] = WI0E; P.whh[0] = WH0E; P.bih[0] = enc_bih0; P.bhh[0] = enc_bhh0;
  P.wih[1] = WI1E; P.whh[1] = WH1E; P.bih[1] = enc_bih1; P.bhh[1] = enc_bhh1;
  P.wih[2] = WI0D; P.whh[2] = WH0D; P.bih[2] = dec_bih0; P.bhh[2] = dec_bhh0;
  P.wih[3] = WI1D; P.whh[3] = WH1D; P.bih[3] = dec_bih1; P.bhh[3] = dec_bhh1;
  P.x[0] = XE;  P.x[1] = YE0; P.x[2] = XD;  P.x[3] = YD0;
  P.y[0] = YE0; P.y[1] = YE1; P.y[2] = YD0; P.y[3] = YD1;
  P.hinit[0] = ZH; P.hinit[1] = ZH;
  P.hinit[2] = YE0 + (size_t)63 * 32 * 512;
  P.hinit[3] = YE1 + (size_t)63 * 32 * 512;
  P.cinit[0] = ZC;  P.cinit[1] = ZC;  P.cinit[2] = CE0; P.cinit[3] = CE1;
  P.cfin[0]  = CE0; P.cfin[1]  = CE1; P.cfin[2]  = CD;  P.cfin[3]  = CD2;
  void* args[1] = {&P};
  hipLaunchCooperativeKernel((void*)lstm_fused, dim3(256), dim3(256), args, 0, stream);

  if (use_waff)
    gemm_aff<<<dim3(16 * 250), dim3(256), 0, stream>>>(YD1, WAFF, aff_b, out);
  else
    gemm_fb<<<dim3(16 * 250), dim3(256), 0, stream>>>(YD1, aff_W, aff_b, out,
                                                      2016, 32000, 512);
}

// Round 17
// 631.978 us; speedup vs baseline: 1.1152x; 1.0119x over previous
//
#include <hip/hip_runtime.h>
#include <hip/hip_bf16.h>

using bf16 = __hip_bfloat16;
typedef __bf16 bf16x8 __attribute__((ext_vector_type(8)));
typedef float f32x4 __attribute__((ext_vector_type(4)));
typedef int i32x4 __attribute__((ext_vector_type(4)));
typedef short short4v __attribute__((ext_vector_type(4)));
typedef short short8v __attribute__((ext_vector_type(8)));

#define DEV __device__ __forceinline__

// B=32, S=64, T=64 (dec 63), V=32000, E=256, H=512, 4H=2048

DEV unsigned short f2bf(float f) {  // RNE float->bf16
  unsigned u = __builtin_bit_cast(unsigned, f);
  u = (u + 0x7fffu + ((u >> 16) & 1u)) >> 16;
  return (unsigned short)u;
}

DEV f32x4 mfma16(bf16x8 a, bf16x8 b, f32x4 c) {
  return __builtin_amdgcn_mfma_f32_16x16x32_bf16(a, b, c, 0, 0, 0);
}

// ---- LLC-coherent (bypass L1+L2) access helpers ------------------------------
DEV void llc_load16(bf16x8* dst, const bf16* p) {  // issue only; caller waits vmcnt
  i32x4 r;
  asm volatile("global_load_dwordx4 %0, %1, off sc0 sc1" : "=v"(r) : "v"(p) : "memory");
  *dst = __builtin_bit_cast(bf16x8, r);
}
DEV void g_load16(bf16x8* dst, const bf16* p) {  // plain (L1/L2-cached), asm-ordered
  i32x4 r;
  asm volatile("global_load_dwordx4 %0, %1, off" : "=v"(r) : "v"(p) : "memory");
  *dst = __builtin_bit_cast(bf16x8, r);
}
DEV void llc_store16(void* p, short8v v) {
  asm volatile("global_store_dwordx4 %0, %1, off sc0 sc1"
               :: "v"(p), "v"(__builtin_bit_cast(i32x4, v)) : "memory");
}
DEV void llc_store_f32(float* p, float v) {
  asm volatile("global_store_dword %0, %1, off sc0 sc1" :: "v"(p), "v"(v) : "memory");
}
DEV bool valid16(bf16x8 v) {  // no dword still holds the 0xFFFFFFFF poison
  i32x4 u = __builtin_bit_cast(i32x4, v);
  return (u[0] != -1) && (u[1] != -1) && (u[2] != -1) && (u[3] != -1);
}

// Data-is-flag slab read with cheap wait loop (R12-verified ordering:
// issue AFTER the x phase — pre-issuing before it regressed 2x in R13).
// 1) opportunistic full load + validate (ready case: 1 LLC RTT)
// 2) not ready: sentinel loop — 4 dwords/lane (one per producer chunk) only
// 3) full reload + validate (rare path)
DEV void poll_slab(const bf16* base, int fl, int koff, bf16x8 a0[4], bf16x8 a1[4]) {
  const bf16* r0 = base + (long)fl * 512 + koff;
  const bf16* r1 = base + (long)(fl + 16) * 512 + koff;
#pragma unroll
  for (int kt = 0; kt < 4; ++kt) {
    llc_load16(&a0[kt], r0 + kt * 32);
    llc_load16(&a1[kt], r1 + kt * 32);
  }
  asm volatile("s_waitcnt vmcnt(0)" ::: "memory");
  {
    bool ok = true;
#pragma unroll
    for (int kt = 0; kt < 4; ++kt) ok = ok && valid16(a0[kt]) && valid16(a1[kt]);
    if (__all(ok)) return;
  }
  // sentinel wait: 1 dword per producer chunk (8x less traffic than full slab)
  while (true) {
    unsigned s0, s1, s2, s3;
    asm volatile(
        "global_load_dword %0, %4, off sc0 sc1\n\t"
        "global_load_dword %1, %5, off sc0 sc1\n\t"
        "global_load_dword %2, %6, off sc0 sc1\n\t"
        "global_load_dword %3, %7, off sc0 sc1\n\t"
        "s_waitcnt vmcnt(0)"
        : "=v"(s0), "=v"(s1), "=v"(s2), "=v"(s3)
        : "v"(r0), "v"(r0 + 32), "v"(r0 + 64), "v"(r0 + 96)
        : "memory");
    bool ok = (s0 != 0xFFFFFFFFu) & (s1 != 0xFFFFFFFFu) & (s2 != 0xFFFFFFFFu) &
              (s3 != 0xFFFFFFFFu);
    if (__all(ok)) break;
    __builtin_amdgcn_s_sleep(1);
  }
  // full reload + validate (covers row fl+16 and every dword)
  while (true) {
#pragma unroll
    for (int kt = 0; kt < 4; ++kt) {
      llc_load16(&a0[kt], r0 + kt * 32);
      llc_load16(&a1[kt], r1 + kt * 32);
    }
    asm volatile("s_waitcnt vmcnt(0)" ::: "memory");
    bool ok = true;
#pragma unroll
    for (int kt = 0; kt < 4; ++kt) ok = ok && valid16(a0[kt]) && valid16(a1[kt]);
    if (__all(ok)) break;
    __builtin_amdgcn_s_sleep(1);
  }
}
DEV float llc_poll_f32(const float* p) {
  while (true) {
    float r;
    asm volatile("global_load_dword %0, %1, off sc0 sc1\n\ts_waitcnt vmcnt(0)"
                 : "=v"(r) : "v"(p) : "memory");
    if (__all(__builtin_bit_cast(unsigned, r) != 0xFFFFFFFFu)) return r;
    __builtin_amdgcn_s_sleep(1);
  }
}

// swizzled LDS addr for [128][64] bf16 tiles: byte ^= (row&7)<<4 — bijective per
// row; fragment reads conflict-free (verified R10-R16)
DEV bf16* swz(bf16* base, int row, int colbyte) {
  return (bf16*)((char*)base + row * 128 + (colbyte ^ ((row & 7) << 4)));
}

// ---------------- fp32 -> bf16 weight conversion --------------------------------
struct ConvJobs {
  const float* src[9];
  bf16* dst[9];
  int n[9];
  int cnt;
};

__global__ void convert_all(ConvJobs jobs) {
  long base = (long)blockIdx.x * blockDim.x + threadIdx.x;
  long stride = (long)gridDim.x * blockDim.x;
  for (int ji = 0; ji < jobs.cnt; ++ji) {
    const float* s = jobs.src[ji];
    bf16* d = jobs.dst[ji];
    long n4 = (long)jobs.n[ji] >> 2;
    for (long i = base; i < n4; i += stride) {
      f32x4 v = *(const f32x4*)(s + i * 4);
      short4v o;
#pragma unroll
      for (int j = 0; j < 4; ++j) o[j] = (short)f2bf(v[j]);
      *(short4v*)((short*)d + i * 4) = o;
    }
  }
}

// ---------------- embedding gather -> bf16, layout [T][B][256] ------------------
__global__ void embed_gather(const int* __restrict__ ids, const float* __restrict__ emb,
                             bf16* __restrict__ out, int rows, int ids_stride) {
  long total = (long)rows * 64;  // 4 elems per item
  long stride = (long)gridDim.x * blockDim.x;
  for (long i = (long)blockIdx.x * blockDim.x + threadIdx.x; i < total; i += stride) {
    int row = (int)(i >> 6);   // row = t*32 + b
    int e = ((int)i & 63) * 4;
    int b = row & 31;
    int t = row >> 5;
    int id = ids[b * ids_stride + t];
    f32x4 v = *(const f32x4*)(emb + (long)id * 256 + e);
    short4v o;
#pragma unroll
    for (int j = 0; j < 4; ++j) o[j] = (short)f2bf(v[j]);
    *(short4v*)((short*)out + (long)row * 256 + e) = o;
  }
}

// ---------------- zero out[:, 0, :] (fallback path only) ------------------------
__global__ void zero_t0(float* __restrict__ out) {
  long total = 32l * 8000;  // float4 per item
  long stride = (long)gridDim.x * blockDim.x;
  f32x4 z{};
  for (long i = (long)blockIdx.x * blockDim.x + threadIdx.x; i < total; i += stride) {
    long b = i / 8000;
    long v = i - b * 8000;
    *(f32x4*)(out + b * 64 * 32000 + v * 4) = z;
  }
}

// ---------------- affine GEMM: out[b*64+t+1] = YD1[t*32+b] @ WAFF^T + affb ------
// 128x128 tile, swizzled LDS (R10-R16-verified). R17: 2-deep register pipeline
// with COUNTED vmcnt — two ping-pong register sets; prologue puts k0+k1 (16
// loads) in flight; steady-state waits vmcnt(8) (drains the older set, keeps
// the newer 8 in flight), writes LDS, issues the replacement set (k+2), then
// MFMAs. Each load gets a full k-step (+slack) to land instead of one short
// MFMA block (the old vmcnt(0) drained a prefetch issued ~32 MFMAs earlier).
// k-loop fully unrolled so the ping-pong index is compile-time constant (no
// scratch). mt==0 blocks zero out[:,0,:] for their column stripe.
__launch_bounds__(256)
__global__ void gemm_aff(const bf16* __restrict__ Ag, const bf16* __restrict__ Wg,
                         const float* __restrict__ affb, float* __restrict__ out) {
  __shared__ __align__(16) bf16 As[128 * 64];
  __shared__ __align__(16) bf16 Bs[128 * 64];
  int mt = blockIdx.x & 15;    // m fastest: concurrent blocks share W stripes
  int ns = blockIdx.x >> 4;
  long m0 = (long)mt * 128, gn0 = (long)ns * 128;
  int tid = threadIdx.x;
  int lane = tid & 63, wave = tid >> 6;
  int wm = wave & 1, wn = wave >> 1;
  int fl = lane & 15, fg = lane >> 4;

  if (mt == 0) {  // zero out[:, 0, gn0:gn0+128): rows b*64, b=0..31
    f32x4 z{};
#pragma unroll
    for (int idx = 0; idx < 4; ++idx) {
      int i = idx * 256 + tid;       // 1024 f32x4 chunks
      int r = i >> 5, c4 = i & 31;   // row b=r, col chunk c4
      *(f32x4*)(out + (long)r * 64 * 32000 + gn0 + c4 * 4) = z;
    }
  }

  f32x4 acc[4][4] = {};
  bf16x8 areg[2][4], wreg[2][4];   // ping-pong register sets (static-indexed)
  int rowv[4], colv[4];
  long arow[4];
#pragma unroll
  for (int i = 0; i < 4; ++i) {
    int e = (i * 256 + tid) * 8;
    rowv[i] = e >> 6; colv[i] = e & 63;
    long ar = m0 + rowv[i]; if (ar >= 2016) ar = 2015;
    arow[i] = ar;
  }
  // prologue: 2 k-steps (16 loads) in flight
#pragma unroll
  for (int s = 0; s < 2; ++s)
#pragma unroll
    for (int i = 0; i < 4; ++i) {
      g_load16(&areg[s][i], Ag + arow[i] * 512 + s * 64 + colv[i]);
      g_load16(&wreg[s][i], Wg + (gn0 + rowv[i]) * 512 + s * 64 + colv[i]);
    }

#pragma unroll
  for (int ks = 0; ks < 8; ++ks) {       // fully unrolled: cur is constant
    const int cur = ks & 1;
    const int k0 = ks * 64;
    if (ks < 7)
      asm volatile("s_waitcnt vmcnt(8)" ::: "memory");  // older set done, newer in flight
    else
      asm volatile("s_waitcnt vmcnt(0)" ::: "memory");  // last set: drain all
    __syncthreads();   // previous MFMA done reading LDS
#pragma unroll
    for (int i = 0; i < 4; ++i) {
      *(bf16x8*)swz(As, rowv[i], colv[i] * 2) = areg[cur][i];
      *(bf16x8*)swz(Bs, rowv[i], colv[i] * 2) = wreg[cur][i];
    }
    __syncthreads();
    if (ks < 6) {  // issue replacement set for k0+128 under this step's MFMAs
#pragma unroll
      for (int i = 0; i < 4; ++i) {
        g_load16(&areg[cur][i], Ag + arow[i] * 512 + (k0 + 128) + colv[i]);
        g_load16(&wreg[cur][i], Wg + (gn0 + rowv[i]) * 512 + (k0 + 128) + colv[i]);
      }
    }
#pragma unroll
    for (int kt = 0; kt < 2; ++kt) {
      bf16x8 af[4], bfr[4];
#pragma unroll
      for (int x = 0; x < 4; ++x)
        af[x] = *(const bf16x8*)swz(As, wm * 64 + x * 16 + fl, (kt * 32 + fg * 8) * 2);
#pragma unroll
      for (int x = 0; x < 4; ++x)
        bfr[x] = *(const bf16x8*)swz(Bs, wn * 64 + x * 16 + fl, (kt * 32 + fg * 8) * 2);
#pragma unroll
      for (int mi = 0; mi < 4; ++mi)
#pragma unroll
        for (int ni = 0; ni < 4; ++ni)
          acc[mi][ni] = mfma16(af[mi], bfr[ni], acc[mi][ni]);
    }
  }
#pragma unroll
  for (int mi = 0; mi < 4; ++mi)
#pragma unroll
    for (int ni = 0; ni < 4; ++ni)
#pragma unroll
      for (int r = 0; r < 4; ++r) {
        long row = m0 + wm * 64 + mi * 16 + fg * 4 + r;
        long col = gn0 + wn * 64 + ni * 16 + fl;
        if (row < 2016) {
          float v = acc[mi][ni][r] + affb[col];
          long orow = (long)(row & 31) * 64 + (row >> 5) + 1;  // b*64 + t + 1
          out[orow * 32000 + col] = v;
        }
      }
}

// ---------------- fallback GEMM (fp32 W in-staging, ws too small for WAFF) ------
__launch_bounds__(256)
__global__ void gemm_fb(const bf16* __restrict__ A, const float* __restrict__ Wf,
                        const float* __restrict__ bias1, float* __restrict__ C,
                        int M, int N, int K) {
  __shared__ __align__(16) bf16 As[128][64];
  __shared__ __align__(16) bf16 Bs[128][64];
  int nm = (M + 127) >> 7;
  int mt_blk = blockIdx.x % nm;
  int nt_blk = blockIdx.x / nm;
  long m0 = (long)mt_blk * 128, n0 = (long)nt_blk * 128;
  int tid = threadIdx.x;
  int lane = tid & 63, wave = tid >> 6;
  int wm = wave & 1, wn = wave >> 1;
  int fl = lane & 15, fg = lane >> 4;
  f32x4 acc[4][4] = {};
  for (int k0 = 0; k0 < K; k0 += 64) {
    __syncthreads();
#pragma unroll
    for (int i = 0; i < 4; ++i) {
      int e = (i * 256 + tid) * 8;
      int row = e >> 6, col = e & 63;
      long ar = m0 + row; if (ar >= M) ar = M - 1;
      *(bf16x8*)(&As[row][col]) = *(const bf16x8*)(A + ar * (long)K + k0 + col);
      long br = n0 + row; if (br >= N) br = N - 1;
      const float* p = Wf + br * (long)K + k0 + col;
      f32x4 v0 = *(const f32x4*)p, v1 = *(const f32x4*)(p + 4);
      short8v o;
#pragma unroll
      for (int j = 0; j < 4; ++j) { o[j] = (short)f2bf(v0[j]); o[j + 4] = (short)f2bf(v1[j]); }
      *(short8v*)(&Bs[row][col]) = o;
    }
    __syncthreads();
#pragma unroll
    for (int kt = 0; kt < 2; ++kt) {
      bf16x8 af[4], bfr[4];
#pragma unroll
      for (int x = 0; x < 4; ++x)
        af[x] = *(const bf16x8*)(&As[wm * 64 + x * 16 + fl][kt * 32 + fg * 8]);
#pragma unroll
      for (int x = 0; x < 4; ++x)
        bfr[x] = *(const bf16x8*)(&Bs[wn * 64 + x * 16 + fl][kt * 32 + fg * 8]);
#pragma unroll
      for (int mi = 0; mi < 4; ++mi)
#pragma unroll
        for (int ni = 0; ni < 4; ++ni)
          acc[mi][ni] = mfma16(af[mi], bfr[ni], acc[mi][ni]);
    }
  }
#pragma unroll
  for (int mi = 0; mi < 4; ++mi)
#pragma unroll
    for (int ni = 0; ni < 4; ++ni)
#pragma unroll
      for (int r = 0; r < 4; ++r) {
        long row = m0 + wm * 64 + mi * 16 + fg * 4 + r;
        long col = n0 + wn * 64 + ni * 16 + fl;
        if (row < M && col < N) {
          float v = acc[mi][ni][r] + bias1[col];
          long orow = (long)(row & 31) * 64 + (row >> 5) + 1;
          C[orow * (long)N + col] = v;
        }
      }
}

// ---------------- fused 4-layer dataflow LSTM (cooperative, 256 blocks) ---------
// BYTE-IDENTICAL to R12/R14/R16 (best measured: 472-476 us, reproduced 4x).
// Block (l, slc): layer l = blockIdx>>6, hidden slice n0 = (blockIdx&63)*8.
// Sentinel data-is-flag sync: h/c buffers poison-filled (0xFF) per launch;
// producers publish coalesced 32x16B straight after the barrier (no drain);
// consumers do opportunistic slab load + poison-validate with a cheap 4-dword
// sentinel fallback. h slab issued AFTER the x phase (R13's pre-issue regressed
// 2x: loads landed before the producer published -> guaranteed fallback path).
struct FusedParams {
  const bf16* wih[4]; const bf16* whh[4];
  const float* bih[4]; const float* bhh[4];
  const bf16* x[4];       // XE, YE0, XD, YD0
  bf16* y[4];             // YE0, YE1, YD0, YD1
  const bf16* hinit[4];   // ZH, ZH, YE0+63*32*512, YE1+63*32*512
  const float* cinit[4];  // ZC, ZC, CE0, CE1
  float* cfin[4];         // CE0, CE1, CD, CD2
};

__launch_bounds__(256)
__global__ void lstm_fused(FusedParams P) {
  __shared__ float part[4][32][33];
  __shared__ __align__(16) unsigned short h_sh[32][8];
  const int tid = threadIdx.x;
  const int lane = tid & 63, wave = tid >> 6;
  const int fl = lane & 15, fg = lane >> 4;
  const int l = blockIdx.x >> 6;
  const int slc = blockIdx.x & 63;
  const int n0 = slc * 8;
  const int b_t = tid & 31, d_t = tid >> 5;
  const int T = (l < 2) ? 64 : 63;
  const int Kx = (l & 1) ? 512 : 256;
  const int xspan = Kx >> 2;   // per-wave x span: 64 or 128
  const int ktx = xspan >> 5;  // 2 or 4
  const bf16* __restrict__ Wih = P.wih[l];
  const bf16* __restrict__ Whh = P.whh[l];
  const bf16* __restrict__ X = P.x[l];
  bf16* __restrict__ Y = P.y[l];
  const bf16* __restrict__ Hinit = P.hinit[l];

  float bsum[4];
#pragma unroll
  for (int gi = 0; gi < 4; ++gi)
    bsum[gi] = P.bih[l][gi * 512 + n0 + d_t] + P.bhh[l][gi * 512 + n0 + d_t];

  // weight fragments in registers: gate-col j = nt*16+fl -> (gate j>>3, dim j&7)
  bf16x8 wfx[2][4], wfh[2][4];
#pragma unroll
  for (int nt = 0; nt < 2; ++nt) {
    int j = nt * 16 + fl;
    long row = (long)(j >> 3) * 512 + n0 + (j & 7);
#pragma unroll
    for (int kt = 0; kt < 4; ++kt) {
      if (kt < ktx)
        wfx[nt][kt] =
            *(const bf16x8*)(Wih + row * (long)Kx + wave * xspan + kt * 32 + fg * 8);
      wfh[nt][kt] = *(const bf16x8*)(Whh + row * 512l + wave * 128 + kt * 32 + fg * 8);
    }
  }
  float c = 0.f;

  for (int t = 0; t < T; ++t) {
    const bf16* xb = X + (long)t * 32 * Kx;
    f32x4 acc[2][2] = {};
    if (l & 1) {
      // x = producer layer's h at step t: data-poll paces the pipeline
      bf16x8 xa0[4], xa1[4];
      poll_slab(xb, fl, wave * 128 + fg * 8, xa0, xa1);
#pragma unroll
      for (int kt = 0; kt < 4; ++kt) {
        acc[0][0] = mfma16(xa0[kt], wfx[0][kt], acc[0][0]);
        acc[0][1] = mfma16(xa0[kt], wfx[1][kt], acc[0][1]);
        acc[1][0] = mfma16(xa1[kt], wfx[0][kt], acc[1][0]);
        acc[1][1] = mfma16(xa1[kt], wfx[1][kt], acc[1][1]);
      }
    } else {
      // XE/XD precomputed in a prior dispatch: normal cached loads
      bf16x8 xa0[2], xa1[2];
#pragma unroll
      for (int kt = 0; kt < 2; ++kt) {
        int k = wave * xspan + kt * 32 + fg * 8;
        xa0[kt] = *(const bf16x8*)(xb + (long)fl * Kx + k);
        xa1[kt] = *(const bf16x8*)(xb + (long)(fl + 16) * Kx + k);
      }
#pragma unroll
      for (int kt = 0; kt < 2; ++kt) {
        acc[0][0] = mfma16(xa0[kt], wfx[0][kt], acc[0][0]);
        acc[0][1] = mfma16(xa0[kt], wfx[1][kt], acc[0][1]);
        acc[1][0] = mfma16(xa1[kt], wfx[0][kt], acc[1][0]);
        acc[1][1] = mfma16(xa1[kt], wfx[1][kt], acc[1][1]);
      }
    }

    // ---- h phase: data-poll own/init h slab (the pacing dependency) ----
    const bf16* hb = (t == 0) ? Hinit : (Y + (long)(t - 1) * 32 * 512);
    bf16x8 ha0[4], ha1[4];
    poll_slab(hb, fl, wave * 128 + fg * 8, ha0, ha1);
    if (t == 0) c = llc_poll_f32(P.cinit[l] + (long)b_t * 512 + n0 + d_t);
#pragma unroll
    for (int kt = 0; kt < 4; ++kt) {
      acc[0][0] = mfma16(ha0[kt], wfh[0][kt], acc[0][0]);
      acc[0][1] = mfma16(ha0[kt], wfh[1][kt], acc[0][1]);
      acc[1][0] = mfma16(ha1[kt], wfh[0][kt], acc[1][0]);
      acc[1][1] = mfma16(ha1[kt], wfh[1][kt], acc[1][1]);
    }
#pragma unroll
    for (int mt = 0; mt < 2; ++mt)
#pragma unroll
      for (int nt = 0; nt < 2; ++nt)
#pragma unroll
        for (int r = 0; r < 4; ++r)
          part[wave][mt * 16 + fg * 4 + r][nt * 16 + fl] = acc[mt][nt][r];
    __syncthreads();

    // reduce 4 K-partials + activations; thread (b_t, d_t)
    float g4[4];
#pragma unroll
    for (int gi = 0; gi < 4; ++gi) {
      int j = gi * 8 + d_t;
      g4[gi] = part[0][b_t][j] + part[1][b_t][j] + part[2][b_t][j] + part[3][b_t][j] +
               bsum[gi];
    }
    float ig = 1.f / (1.f + __expf(-g4[0]));
    float ff = 1.f / (1.f + __expf(-g4[1]));
    float gg = tanhf(g4[2]);
    float og = 1.f / (1.f + __expf(-g4[3]));
    c = ff * c + ig * gg;
    float h = og * tanhf(c);
    h_sh[b_t][d_t] = f2bf(h);
    if (t == T - 1)
      llc_store_f32(P.cfin[l] + (long)b_t * 512 + n0 + d_t, c);  // data-polled
    __syncthreads();  // h_sh complete; also part[] reuse guard
    // wave 0 publishes coalesced, NO drain/flag (data IS the flag);
    // waves 1-3 run ahead into next step immediately
    if (wave == 0 && lane < 32)
      llc_store16((unsigned short*)Y + ((long)t * 32 + lane) * 512 + n0,
                  *(const short8v*)(&h_sh[lane][0]));
  }
}

extern "C" void kernel_launch(void* const* d_in, const int* in_sizes, int n_in,
                              void* d_out, int out_size, void* d_ws, size_t ws_size,
                              hipStream_t stream) {
  (void)in_sizes; (void)n_in; (void)out_size;
  const int*   source   = (const int*)d_in[0];
  const int*   target   = (const int*)d_in[1];
  const float* enc_emb  = (const float*)d_in[2];
  const float* enc_Wih0 = (const float*)d_in[3];
  const float* enc_Whh0 = (const float*)d_in[4];
  const float* enc_bih0 = (const float*)d_in[5];
  const float* enc_bhh0 = (const float*)d_in[6];
  const float* enc_Wih1 = (const float*)d_in[7];
  const float* enc_Whh1 = (const float*)d_in[8];
  const float* enc_bih1 = (const float*)d_in[9];
  const float* enc_bhh1 = (const float*)d_in[10];
  const float* dec_emb  = (const float*)d_in[11];
  const float* dec_Wih0 = (const float*)d_in[12];
  const float* dec_Whh0 = (const float*)d_in[13];
  const float* dec_bih0 = (const float*)d_in[14];
  const float* dec_bhh0 = (const float*)d_in[15];
  const float* dec_Wih1 = (const float*)d_in[16];
  const float* dec_Whh1 = (const float*)d_in[17];
  const float* dec_bih1 = (const float*)d_in[18];
  const float* dec_bhh1 = (const float*)d_in[19];
  const float* aff_W    = (const float*)d_in[20];
  const float* aff_b    = (const float*)d_in[21];
  float* out = (float*)d_out;

  size_t off = 0;
  auto alc = [&](size_t bytes) {
    char* p = (char*)d_ws + off;
    off += (bytes + 255) & ~(size_t)255;
    return (void*)p;
  };
  // zero region (valid-zero h/c inits)
  bf16*  ZH  = (bf16*)alc(32 * 512 * 2);
  float* ZC  = (float*)alc(32 * 512 * 4);
  size_t zero_span = off;
  // poison region (data-is-flag buffers, re-poisoned 0xFF every launch)
  size_t poison_begin = off;
  float* CE0 = (float*)alc(32 * 512 * 4);
  float* CE1 = (float*)alc(32 * 512 * 4);
  bf16*  YE0 = (bf16*)alc((size_t)2048 * 512 * 2);   // [64][32][512]
  bf16*  YE1 = (bf16*)alc((size_t)2048 * 512 * 2);
  bf16*  YD0 = (bf16*)alc((size_t)2016 * 512 * 2);   // [63][32][512]
  bf16*  YD1 = (bf16*)alc((size_t)2016 * 512 * 2);
  size_t poison_end = off;
  // plain scratch
  float* CD  = (float*)alc(32 * 512 * 4);
  float* CD2 = (float*)alc(32 * 512 * 4);
  bf16*  XE  = (bf16*)alc((size_t)2048 * 256 * 2);   // [64][32][256]
  bf16*  XD  = (bf16*)alc((size_t)2016 * 256 * 2);   // [63][32][256]
  bf16*  WI0E = (bf16*)alc((size_t)2048 * 256 * 2);
  bf16*  WH0E = (bf16*)alc((size_t)2048 * 512 * 2);
  bf16*  WI1E = (bf16*)alc((size_t)2048 * 512 * 2);
  bf16*  WH1E = (bf16*)alc((size_t)2048 * 512 * 2);
  bf16*  WI0D = (bf16*)alc((size_t)2048 * 256 * 2);
  bf16*  WH0D = (bf16*)alc((size_t)2048 * 512 * 2);
  bf16*  WI1D = (bf16*)alc((size_t)2048 * 512 * 2);
  bf16*  WH1D = (bf16*)alc((size_t)2048 * 512 * 2);
  bf16*  WAFF = (bf16*)alc((size_t)32000 * 512 * 2);  // 32.8 MB, optional
  bool use_waff = (off <= ws_size);

  hipMemsetAsync(d_ws, 0, zero_span, stream);
  hipMemsetAsync((char*)d_ws + poison_begin, 0xFF, poison_end - poison_begin, stream);

  ConvJobs cj;
  cj.src[0] = enc_Wih0; cj.dst[0] = WI0E; cj.n[0] = 2048 * 256;
  cj.src[1] = enc_Whh0; cj.dst[1] = WH0E; cj.n[1] = 2048 * 512;
  cj.src[2] = enc_Wih1; cj.dst[2] = WI1E; cj.n[2] = 2048 * 512;
  cj.src[3] = enc_Whh1; cj.dst[3] = WH1E; cj.n[3] = 2048 * 512;
  cj.src[4] = dec_Wih0; cj.dst[4] = WI0D; cj.n[4] = 2048 * 256;
  cj.src[5] = dec_Whh0; cj.dst[5] = WH0D; cj.n[5] = 2048 * 512;
  cj.src[6] = dec_Wih1; cj.dst[6] = WI1D; cj.n[6] = 2048 * 512;
  cj.src[7] = dec_Whh1; cj.dst[7] = WH1D; cj.n[7] = 2048 * 512;
  cj.cnt = 8;
  if (use_waff) {
    cj.src[8] = aff_W; cj.dst[8] = WAFF; cj.n[8] = 32000 * 512; cj.cnt = 9;
  }
  convert_all<<<dim3(1024), dim3(256), 0, stream>>>(cj);

  embed_gather<<<dim3(512), dim3(256), 0, stream>>>(source, enc_emb, XE, 2048, 64);
  embed_gather<<<dim3(512), dim3(256), 0, stream>>>(target, dec_emb, XD, 2016, 64);
  if (!use_waff) zero_t0<<<dim3(1000), dim3(256), 0, stream>>>(out);

  FusedParams P;
  P.wih[0] = WI0E; P.whh[0] = WH0E; P.bih[0] = enc_bih0; P.bhh[0] = enc_bhh0;
  P.wih[1] = WI1E; P.whh[1] = WH1E; P.bih[1] = enc_bih1; P.bhh[1] = enc_bhh1;
  P.wih[2] = WI0D; P.whh[2] = WH0D; P.bih[2] = dec_bih0; P.bhh[2] = dec_bhh0;
  P.wih[3] = WI1D; P.whh[3] = WH1D; P.bih[3] = dec_bih1; P.bhh[3] = dec_bhh1;
  P.x[0] = XE;  P.x[1] = YE0; P.x[2] = XD;  P.x[3] = YD0;
  P.y[0] = YE0; P.y[1] = YE1; P.y[2] = YD0; P.y[3] = YD1;
  P.hinit[0] = ZH; P.hinit[1] = ZH;
  P.hinit[2] = YE0 + (size_t)63 * 32 * 512;
  P.hinit[3] = YE1 + (size_t)63 * 32 * 512;
  P.cinit[0] = ZC;  P.cinit[1] = ZC;  P.cinit[2] = CE0; P.cinit[3] = CE1;
  P.cfin[0]  = CE0; P.cfin[1]  = CE1; P.cfin[2]  = CD;  P.cfin[3]  = CD2;
  void* args[1] = {&P};
  hipLaunchCooperativeKernel((void*)lstm_fused, dim3(256), dim3(256), args, 0, stream);

  if (use_waff)
    gemm_aff<<<dim3(16 * 250), dim3(256), 0, stream>>>(YD1, WAFF, aff_b, out);
  else
    gemm_fb<<<dim3(16 * 250), dim3(256), 0, stream>>>(YD1, aff_W, aff_b, out,
                                                      2016, 32000, 512);
}